// Round 13
// baseline (951.662 us; speedup 1.0000x reference)
//
#include <hip/hip_runtime.h>
#include <math.h>
#include <limits.h>

#define D 64
#define K 5
#define LK 8                  // per-lane / per-split candidate list length
#define GK 12                 // global candidates rescored per row
#define NSPLIT 16
#define NTILES 625            // 10000 / 16 exactly
#define ROWBLK 157            // ceil(10000/64)
#define NCOMP (ROWBLK * NSPLIT)   // 2512 compute blocks
#define NMIX  3024                // zero+compute interleaved region (504 zero)
#define NZERO 504
typedef unsigned int u32;
typedef unsigned long long u64;
typedef __bf16 bf16x8 __attribute__((ext_vector_type(8)));
typedef float  f32x4v __attribute__((ext_vector_type(4)));

// v_med3_u32 (GCN3+; no HIP builtin)
__device__ __forceinline__ u32 med3u(u32 a, u32 b, u32 c) {
    u32 r;
    asm("v_med3_u32 %0, %1, %2, %3" : "=v"(r) : "v"(a), "v"(b), "v"(c));
    return r;
}

// ---- u32 key: [31:14] = top bits of FULL monotone fp32 map, [13:0] = ~idx.
// bigger key == (bigger value, then lower idx). ----
__device__ __forceinline__ u32 pack32(float v, int idx) {
    u32 u = __float_as_uint(v);
    u ^= ((u32)((int)u >> 31)) | 0x80000000u;
    return (u & 0xFFFFC000u) | ((~(u32)idx) & 0x3FFFu);
}
__device__ __forceinline__ int idx32(u32 key) { return (int)((~key) & 0x3FFFu); }

// exact final key (value, then lower idx)
__device__ __forceinline__ u64 packKV(float v, int idx) {
    u32 u = __float_as_uint(v);
    u ^= ((u32)((int)u >> 31)) | 0x80000000u;
    return ((u64)u << 32) | (u32)(~idx);
}
__device__ __forceinline__ float unpackV(u64 key) {
    u32 hu = (u32)(key >> 32);
    return (hu & 0x80000000u) ? __uint_as_float(hu & 0x7fffffffu)
                              : __uint_as_float(~hu);
}

// branchless merge of two sorted-desc lists, keep first LO into a[]
template<int LO, int LA, int LB, typename T>
__device__ __forceinline__ void mergeKeep(T a[LA], const T b[LB]) {
    T A[LA], B[LB], out[LO];
#pragma unroll
    for (int i = 0; i < LA; ++i) A[i] = a[i];
#pragma unroll
    for (int i = 0; i < LB; ++i) B[i] = b[i];
#pragma unroll
    for (int m = 0; m < LO; ++m) {
        bool ta = A[0] >= B[0];
        out[m] = ta ? A[0] : B[0];
#pragma unroll
        for (int i = 0; i < LA - 1; ++i) A[i] = ta ? A[i + 1] : A[i];
        A[LA - 1] = ta ? (T)0 : A[LA - 1];
#pragma unroll
        for (int i = 0; i < LB - 1; ++i) B[i] = ta ? B[i] : B[i + 1];
        B[LB - 1] = ta ? B[LB - 1] : (T)0;
    }
#pragma unroll
    for (int m = 0; m < LO; ++m) a[m] = out[m];
}

// ---------------------------------------------------------------------------
// Prep: repack x into MFMA-fragment order + row norms + zero the sync counters.
// ---------------------------------------------------------------------------
__global__ __launch_bounds__(256) void prep(
    const float* __restrict__ x, __bf16* __restrict__ xbA, float* __restrict__ xxf,
    u32* __restrict__ ctrs, int N)
{
    int g = blockIdx.x * 256 + threadIdx.x;
    if (g < 2) ctrs[g] = 0u;                     // [0]=zeroDone, [1]=compDone
    const int REPACK = NTILES * 2 * 64;          // 80000
    if (g < REPACK) {
        int tile = g >> 7;
        int rem  = g & 127;
        int kh   = rem >> 6;
        int lane = rem & 63;
        int q = lane >> 4, r = lane & 15;
        int row = tile * 16 + r;
        int k0  = kh * 32 + q * 8;
        const float4* p = (const float4*)(x + (size_t)row * D + k0);
        float4 v0 = p[0], v1 = p[1];
        bf16x8 o;
        o[0] = (__bf16)v0.x; o[1] = (__bf16)v0.y; o[2] = (__bf16)v0.z; o[3] = (__bf16)v0.w;
        o[4] = (__bf16)v1.x; o[5] = (__bf16)v1.y; o[6] = (__bf16)v1.z; o[7] = (__bf16)v1.w;
        ((bf16x8*)xbA)[g] = o;
        return;
    }
    int i = g - REPACK;
    if (i >= N) return;
    const float4* p = (const float4*)(x + (size_t)i * D);
    float s = 0.f;
#pragma unroll
    for (int t = 0; t < 16; ++t) {
        float4 v = p[t];
        s += v.x * v.x + v.y * v.y + v.z * v.z + v.w * v.w;
    }
    xxf[i] = s;
}

// ---------------------------------------------------------------------------
// Fused, block-specialized dispatch:
//   bx in [0,NMIX), bx%6==0 : ZERO block (pure NT store stream); counter++.
//   bx in [0,NMIX), else    : COMPUTE block (MFMA + med3 top-8); counter++.
//   bx >= NMIX              : RESCORE block — spins (s_sleep) until all zero
//                             AND compute blocks are done, then merge/rescore/
//                             scatter. <=157 spinners can never fill the
//                             ~2048 resident slots -> no deadlock regardless
//                             of dispatch order (G16-safe).
// ---------------------------------------------------------------------------
__global__ __launch_bounds__(256) void fused(
    const __bf16* __restrict__ xbA, const float* __restrict__ xxf,
    const float* __restrict__ x, int N,
    u32* __restrict__ wsK, u32* __restrict__ ctrs,
    float* __restrict__ outZ, long long totalF4, int f4PerZ)
{
    const int bx  = blockIdx.x;
    const int tid = threadIdx.x;

    if (bx < NMIX && bx % 6 == 0) {
        // ---------------- zero block ----------------
        int zid = bx / 6;
        long long s = (long long)zid * f4PerZ;
        long long e = s + f4PerZ; if (e > totalF4) e = totalF4;
        const f32x4v z = {0.f, 0.f, 0.f, 0.f};
        for (long long i = s + tid; i < e; i += 256)
            __builtin_nontemporal_store(z, (f32x4v*)(outZ + 4 * i));
        __threadfence();
        __syncthreads();
        if (tid == 0) atomicAdd(&ctrs[0], 1u);
        return;
    }

    if (bx < NMIX) {
        // ---------------- compute block ----------------
        const int cid = bx - (bx / 6 + 1);           // dense index over non-zero blocks
        if (cid >= NCOMP) { __syncthreads(); if (tid == 0) atomicAdd(&ctrs[1], 1u); return; }
        const int split = cid / ROWBLK;              // 0..15
        const int rb    = cid - split * ROWBLK;      // 0..156

        const int lane = tid & 63;
        const int wave = tid >> 6;
        const int l15  = lane & 15;
        const int q    = lane >> 4;                  // col quad
        const int r0 = rb * 64 + wave * 16;

        const bf16x8* fb = (const bf16x8*)xbA;       // fragment base, 128 per tile

        int bt = r0 >> 4; if (bt > NTILES - 1) bt = NTILES - 1;
        const bf16x8 B0 = fb[bt * 128 + lane];
        const bf16x8 B1 = fb[bt * 128 + 64 + lane];

        const bf16x8* ap = fb + (size_t)split * 128 + lane;
        const float* xcp = xxf + split * 16 + q * 4;
        int cbase = split * 16 + q * 4;
        const int apBump = NSPLIT * 128;
        const int xcBump = NSPLIT * 16;

        u32 L[LK];
#pragma unroll
        for (int m = 0; m < LK; ++m) L[m] = 0u;

        for (int t = split; t < NTILES; t += NSPLIT) {
            const bf16x8 A0 = ap[0];
            const bf16x8 A1 = ap[64];
            const f32x4v xc = *(const f32x4v*)xcp;
            ap += apBump;
            xcp += xcBump;

            f32x4v acc = {0.f, 0.f, 0.f, 0.f};
            acc = __builtin_amdgcn_mfma_f32_16x16x32_bf16(A0, B0, acc, 0, 0, 0);
            acc = __builtin_amdgcn_mfma_f32_16x16x32_bf16(A1, B1, acc, 0, 0, 0);

#pragma unroll
            for (int v = 0; v < 4; ++v) {
                float dk = fmaf(-0.5f, xc[v], acc[v]);
                u32 key = pack32(dk, cbase + v);
                u32 n0 = max(L[0], key);
                u32 n1 = med3u(L[0], L[1], key);
                u32 n2 = med3u(L[1], L[2], key);
                u32 n3 = med3u(L[2], L[3], key);
                u32 n4 = med3u(L[3], L[4], key);
                u32 n5 = med3u(L[4], L[5], key);
                u32 n6 = med3u(L[5], L[6], key);
                u32 n7 = med3u(L[6], L[7], key);
                L[0]=n0; L[1]=n1; L[2]=n2; L[3]=n3; L[4]=n4; L[5]=n5; L[6]=n6; L[7]=n7;
            }
            cbase += xcBump;
        }

#pragma unroll
        for (int mask = 16; mask <= 32; mask <<= 1) {
            u32 P[LK];
#pragma unroll
            for (int m = 0; m < LK; ++m) P[m] = (u32)__shfl_xor((int)L[m], mask);
            mergeKeep<LK, LK, LK, u32>(L, P);
        }

        if (lane < 16) {
            int row = r0 + l15;
            if (row < N) {
                u32* dst = wsK + ((size_t)row * NSPLIT + split) * LK;
#pragma unroll
                for (int m = 0; m < LK; ++m) dst[m] = L[m];
            }
        }
        __threadfence();
        __syncthreads();
        if (tid == 0) atomicAdd(&ctrs[1], 1u);
        return;
    }

    // ---------------- rescore block (spin tail) ----------------
    if (tid == 0) {
        while (__hip_atomic_load(&ctrs[0], __ATOMIC_ACQUIRE, __HIP_MEMORY_SCOPE_AGENT) < (u32)NZERO ||
               __hip_atomic_load(&ctrs[1], __ATOMIC_ACQUIRE, __HIP_MEMORY_SCOPE_AGENT) < (u32)(NMIX - NZERO))
            __builtin_amdgcn_s_sleep(8);
    }
    __syncthreads();
    __threadfence();

    const int rbx  = bx - NMIX;                  // 0..156
    const int lane = tid & 63;
    const int wave = tid >> 6;
    const int sub  = lane & 3;
    const int row  = rbx * 64 + wave * 16 + (lane >> 2);
    const bool vrow = (row < N);
    const int rr = vrow ? row : 0;
    float* out = outZ;

    u32 cur[GK];
    {
        const u32* Lp = wsK + ((size_t)rr * NSPLIT + 4 * sub) * LK;
#pragma unroll
        for (int m = 0; m < LK; ++m) cur[m] = Lp[m];
#pragma unroll
        for (int m = LK; m < GK; ++m) cur[m] = 0u;
#pragma unroll
        for (int l = 1; l < 4; ++l) {
            u32 b[LK];
#pragma unroll
            for (int m = 0; m < LK; ++m) b[m] = Lp[l * LK + m];
            mergeKeep<GK, GK, LK, u32>(cur, b);
        }
    }
#pragma unroll
    for (int mask = 1; mask <= 2; mask <<= 1) {
        u32 P[GK];
#pragma unroll
        for (int m = 0; m < GK; ++m) P[m] = (u32)__shfl_xor((int)cur[m], mask);
        mergeKeep<GK, GK, GK, u32>(cur, P);
    }

    const float nxi = xxf[rr];
    int   cj[3]; bool cval[3];
    float d[3] = {0.f, 0.f, 0.f};
    const f32x4v* pj[3];
#pragma unroll
    for (int c = 0; c < 3; ++c) {
        int j = idx32(cur[sub * 3 + c]);
        cval[c] = (j < N) && (cur[sub * 3 + c] != 0u);
        cj[c] = cval[c] ? j : 0;
        pj[c] = (const f32x4v*)(x + (size_t)cj[c] * D);
    }
    const f32x4v* xip = (const f32x4v*)(x + (size_t)rr * D);
#pragma unroll
    for (int t = 0; t < 16; ++t) {
        const f32x4v xv = xip[t];
#pragma unroll
        for (int c = 0; c < 3; ++c) {
            const f32x4v pv = pj[c][t];
            d[c] = fmaf(xv[0], pv[0], d[c]);
            d[c] = fmaf(xv[1], pv[1], d[c]);
            d[c] = fmaf(xv[2], pv[2], d[c]);
            d[c] = fmaf(xv[3], pv[3], d[c]);
        }
    }
    u64 F[K];
#pragma unroll
    for (int c = 0; c < 3; ++c) {
        float val = 2.f * d[c] - nxi - xxf[cj[c]];
        F[c] = cval[c] ? packKV(val, cj[c]) : 0ull;
    }
    F[3] = 0ull; F[4] = 0ull;
    { u64 a0=F[0],a1=F[1],a2=F[2];
      if (a0 < a1) { u64 t0=a0; a0=a1; a1=t0; }
      if (a1 < a2) { u64 t0=a1; a1=a2; a2=t0; }
      if (a0 < a1) { u64 t0=a0; a0=a1; a1=t0; }
      F[0]=a0; F[1]=a1; F[2]=a2; }
#pragma unroll
    for (int mask = 1; mask <= 2; mask <<= 1) {
        u64 P[K];
#pragma unroll
        for (int m = 0; m < K; ++m) P[m] = __shfl_xor(F[m], mask);
        mergeKeep<K, K, K, u64>(F, P);
    }

    if (sub == 0 && vrow) {
#pragma unroll
        for (int m = 0; m < K; ++m) {
            int j = (int)(~(u32)F[m]);
            if ((unsigned)j < (unsigned)N && j != row) {
                float v = unpackV(F[m]);
                atomicAdd(out + (size_t)row * N + j, v);
                atomicAdd(out + (size_t)j * N + row, v);
            }
        }
    }
}

// ---------------------------------------------------------------------------
extern "C" void kernel_launch(void* const* d_in, const int* in_sizes, int n_in,
                              void* d_out, int out_size, void* d_ws, size_t ws_size,
                              hipStream_t stream) {
    const float* x = (const float*)d_in[0];
    const int N = in_sizes[0] / D;          // 10000
    float* out = (float*)d_out;

    // Workspace: xbA | xxf | wsK | ctrs  (~7.5 MB)
    const size_t oXB = 0;
    const size_t oXX = ((size_t)NTILES * 2 * 64 * 8 * 2 + 255) & ~255ull;
    const size_t oWK = (oXX + (size_t)N * 4 + 255) & ~255ull;
    const size_t oCT = (oWK + (size_t)N * NSPLIT * LK * 4 + 255) & ~255ull;
    __bf16* xbA = (__bf16*)((char*)d_ws + oXB);
    float*  xxf = (float*)((char*)d_ws + oXX);
    u32*    wsK = (u32*)((char*)d_ws + oWK);
    u32*    ctrs = (u32*)((char*)d_ws + oCT);

    const int prepThreads = NTILES * 2 * 64 + N;         // 90000
    prep<<<(prepThreads + 255) / 256, 256, 0, stream>>>(x, xbA, xxf, ctrs, N);

    long long totalF4 = (long long)out_size / 4;         // 25e6
    int f4PerZ = (int)((totalF4 + NZERO - 1) / NZERO);   // ~49604
    fused<<<NMIX + ROWBLK, 256, 0, stream>>>(
        xbA, xxf, x, N, wsK, ctrs, out, totalF4, f4PerZ);
}

// Round 14
// 451.014 us; speedup vs baseline: 2.1100x; 2.1100x over previous
//
#include <hip/hip_runtime.h>
#include <math.h>
#include <limits.h>

#define D 64
#define K 5
#define LK 8                  // per-lane / per-split candidate list length
#define GK 12                 // global candidates rescored per row
#define NSPLIT 16
#define NTILES 625            // 10000 / 16 exactly
#define ROWBLK 157            // ceil(10000/64)
#define NCOMP (ROWBLK * NSPLIT)   // 2512 compute blocks
typedef unsigned int u32;
typedef unsigned long long u64;
typedef __bf16 bf16x8 __attribute__((ext_vector_type(8)));
typedef float  f32x4v __attribute__((ext_vector_type(4)));

// v_med3_u32 (GCN3+; no HIP builtin)
__device__ __forceinline__ u32 med3u(u32 a, u32 b, u32 c) {
    u32 r;
    asm("v_med3_u32 %0, %1, %2, %3" : "=v"(r) : "v"(a), "v"(b), "v"(c));
    return r;
}

// ---- u32 key: [31:14] = top bits of FULL monotone fp32 map, [13:0] = ~idx.
// bigger key == (bigger value, then lower idx). ----
__device__ __forceinline__ u32 pack32(float v, int idx) {
    u32 u = __float_as_uint(v);
    u ^= ((u32)((int)u >> 31)) | 0x80000000u;
    return (u & 0xFFFFC000u) | ((~(u32)idx) & 0x3FFFu);
}
__device__ __forceinline__ int idx32(u32 key) { return (int)((~key) & 0x3FFFu); }

// exact final key (value, then lower idx)
__device__ __forceinline__ u64 packKV(float v, int idx) {
    u32 u = __float_as_uint(v);
    u ^= ((u32)((int)u >> 31)) | 0x80000000u;
    return ((u64)u << 32) | (u32)(~idx);
}
__device__ __forceinline__ float unpackV(u64 key) {
    u32 hu = (u32)(key >> 32);
    return (hu & 0x80000000u) ? __uint_as_float(hu & 0x7fffffffu)
                              : __uint_as_float(~hu);
}

// branchless merge of two sorted-desc lists, keep first LO into a[]
template<int LO, int LA, int LB, typename T>
__device__ __forceinline__ void mergeKeep(T a[LA], const T b[LB]) {
    T A[LA], B[LB], out[LO];
#pragma unroll
    for (int i = 0; i < LA; ++i) A[i] = a[i];
#pragma unroll
    for (int i = 0; i < LB; ++i) B[i] = b[i];
#pragma unroll
    for (int m = 0; m < LO; ++m) {
        bool ta = A[0] >= B[0];
        out[m] = ta ? A[0] : B[0];
#pragma unroll
        for (int i = 0; i < LA - 1; ++i) A[i] = ta ? A[i + 1] : A[i];
        A[LA - 1] = ta ? (T)0 : A[LA - 1];
#pragma unroll
        for (int i = 0; i < LB - 1; ++i) B[i] = ta ? B[i] : B[i + 1];
        B[LB - 1] = ta ? B[LB - 1] : (T)0;
    }
#pragma unroll
    for (int m = 0; m < LO; ++m) a[m] = out[m];
}

// ---------------------------------------------------------------------------
// Prep: repack x into MFMA-fragment order + row norms.
// xbA[tile][khalf][lane][8 bf16]: lane = q*16+r holds x[tile*16+r][kh*32+q*8..+8).
// ---------------------------------------------------------------------------
__global__ __launch_bounds__(256) void prep(
    const float* __restrict__ x, __bf16* __restrict__ xbA, float* __restrict__ xxf, int N)
{
    int g = blockIdx.x * 256 + threadIdx.x;
    const int REPACK = NTILES * 2 * 64;          // 80000
    if (g < REPACK) {
        int tile = g >> 7;
        int rem  = g & 127;
        int kh   = rem >> 6;
        int lane = rem & 63;
        int q = lane >> 4, r = lane & 15;
        int row = tile * 16 + r;
        int k0  = kh * 32 + q * 8;
        const float4* p = (const float4*)(x + (size_t)row * D + k0);
        float4 v0 = p[0], v1 = p[1];
        bf16x8 o;
        o[0] = (__bf16)v0.x; o[1] = (__bf16)v0.y; o[2] = (__bf16)v0.z; o[3] = (__bf16)v0.w;
        o[4] = (__bf16)v1.x; o[5] = (__bf16)v1.y; o[6] = (__bf16)v1.z; o[7] = (__bf16)v1.w;
        ((bf16x8*)xbA)[g] = o;
        return;
    }
    int i = g - REPACK;
    if (i >= N) return;
    const float4* p = (const float4*)(x + (size_t)i * D);
    float s = 0.f;
#pragma unroll
    for (int t = 0; t < 16; ++t) {
        float4 v = p[t];
        s += v.x * v.x + v.y * v.y + v.z * v.z + v.w * v.w;
    }
    xxf[i] = s;
}

// ---------------------------------------------------------------------------
// Block-specialized: blocks with bx%6==0 are PURE ZERO blocks (NT store
// stream only — nothing else in their vmcnt queue); the rest are PURE COMPUTE
// blocks (no stores in the K-loop, so the in-order vmcnt retirement never
// couples an A-load wait to an HBM store ack). Both co-resident per CU ->
// write stream and compute overlap at the scheduler level.
// ---------------------------------------------------------------------------
__global__ __launch_bounds__(256) void topk_zero_mfma(
    const __bf16* __restrict__ xbA, const float* __restrict__ xxf, int N,
    u32* __restrict__ wsK, float* __restrict__ outZ, long long totalF4,
    int nZero, int f4PerZ)
{
    const int bx  = blockIdx.x;
    const int tid = threadIdx.x;

    if (bx % 6 == 0) {
        // ---------------- zero block ----------------
        int zid = bx / 6;
        if (zid >= nZero) return;
        long long s = (long long)zid * f4PerZ;
        long long e = s + f4PerZ; if (e > totalF4) e = totalF4;
        const f32x4v z = {0.f, 0.f, 0.f, 0.f};
        for (long long i = s + tid; i < e; i += 256)
            __builtin_nontemporal_store(z, (f32x4v*)(outZ + 4 * i));
        return;
    }

    // ---------------- compute block ----------------
    const int cid = bx - (bx / 6 + 1);           // dense index over non-zero blocks
    if (cid >= NCOMP) return;
    const int split = cid / ROWBLK;              // 0..15
    const int rb    = cid - split * ROWBLK;      // 0..156

    const int lane = tid & 63;
    const int wave = tid >> 6;
    const int l15  = lane & 15;
    const int q    = lane >> 4;                  // col quad
    const int r0 = rb * 64 + wave * 16;

    const bf16x8* fb = (const bf16x8*)xbA;       // fragment base, 128 per tile

    // B fragments: my 16-row tile (clamped for tail waves), held in regs
    int bt = r0 >> 4; if (bt > NTILES - 1) bt = NTILES - 1;
    const bf16x8 B0 = fb[bt * 128 + lane];
    const bf16x8 B1 = fb[bt * 128 + 64 + lane];

    // pointer-bumped loop state
    const bf16x8* ap = fb + (size_t)split * 128 + lane;
    const float* xcp = xxf + split * 16 + q * 4;
    int cbase = split * 16 + q * 4;
    const int apBump = NSPLIT * 128;
    const int xcBump = NSPLIT * 16;

    u32 L[LK];
#pragma unroll
    for (int m = 0; m < LK; ++m) L[m] = 0u;      // 0 < any real packed key

    for (int t = split; t < NTILES; t += NSPLIT) {
        const bf16x8 A0 = ap[0];
        const bf16x8 A1 = ap[64];
        const f32x4v xc = *(const f32x4v*)xcp;
        ap += apBump;
        xcp += xcBump;

        f32x4v acc = {0.f, 0.f, 0.f, 0.f};
        acc = __builtin_amdgcn_mfma_f32_16x16x32_bf16(A0, B0, acc, 0, 0, 0);
        acc = __builtin_amdgcn_mfma_f32_16x16x32_bf16(A1, B1, acc, 0, 0, 0);

        // full monotone key map + med3 insertion
#pragma unroll
        for (int v = 0; v < 4; ++v) {
            float dk = fmaf(-0.5f, xc[v], acc[v]);   // ordering == distance ordering
            u32 key = pack32(dk, cbase + v);
            u32 n0 = max(L[0], key);
            u32 n1 = med3u(L[0], L[1], key);
            u32 n2 = med3u(L[1], L[2], key);
            u32 n3 = med3u(L[2], L[3], key);
            u32 n4 = med3u(L[3], L[4], key);
            u32 n5 = med3u(L[4], L[5], key);
            u32 n6 = med3u(L[5], L[6], key);
            u32 n7 = med3u(L[6], L[7], key);
            L[0]=n0; L[1]=n1; L[2]=n2; L[3]=n3; L[4]=n4; L[5]=n5; L[6]=n6; L[7]=n7;
        }
        cbase += xcBump;
    }

    // butterfly merge across the 4 quads sharing a row
#pragma unroll
    for (int mask = 16; mask <= 32; mask <<= 1) {
        u32 P[LK];
#pragma unroll
        for (int m = 0; m < LK; ++m) P[m] = (u32)__shfl_xor((int)L[m], mask);
        mergeKeep<LK, LK, LK, u32>(L, P);
    }

    if (lane < 16) {
        int row = r0 + l15;
        if (row < N) {
            u32* dst = wsK + ((size_t)row * NSPLIT + split) * LK;
#pragma unroll
            for (int m = 0; m < LK; ++m) dst[m] = L[m];
        }
    }
}

// ---------------------------------------------------------------------------
// 4 lanes per row. Each lane merges 4 split-lists (u32); 2 shfl_xor
// butterflies give the global bf16-top-12. Each lane rescores 3 candidates in
// exact fp32; final top-5 via exact packed-u64 butterfly (== reference
// tie-break). Lane 0 of each row does the symmetric atomic scatter.
// ---------------------------------------------------------------------------
__global__ __launch_bounds__(256) void rescore_scatter(
    const u32* __restrict__ wsK, const float* __restrict__ x, const float* __restrict__ xxf,
    float* __restrict__ out, int N)
{
    const int lane = threadIdx.x & 63;
    const int wave = threadIdx.x >> 6;
    const int sub  = lane & 3;
    const int row  = blockIdx.x * 64 + wave * 16 + (lane >> 2);
    const bool vrow = (row < N);
    const int rr = vrow ? row : 0;

    // merge my 4 lists, then butterfly to global top-12
    u32 cur[GK];
    {
        const u32* Lp = wsK + ((size_t)rr * NSPLIT + 4 * sub) * LK;
#pragma unroll
        for (int m = 0; m < LK; ++m) cur[m] = Lp[m];
#pragma unroll
        for (int m = LK; m < GK; ++m) cur[m] = 0u;
#pragma unroll
        for (int l = 1; l < 4; ++l) {
            u32 b[LK];
#pragma unroll
            for (int m = 0; m < LK; ++m) b[m] = Lp[l * LK + m];
            mergeKeep<GK, GK, LK, u32>(cur, b);
        }
    }
#pragma unroll
    for (int mask = 1; mask <= 2; mask <<= 1) {
        u32 P[GK];
#pragma unroll
        for (int m = 0; m < GK; ++m) P[m] = (u32)__shfl_xor((int)cur[m], mask);
        mergeKeep<GK, GK, GK, u32>(cur, P);
    }

    // exact fp32 rescore of my 3 candidates
    const float nxi = xxf[rr];
    int   cj[3]; bool cval[3];
    float d[3] = {0.f, 0.f, 0.f};
    const f32x4v* pj[3];
#pragma unroll
    for (int c = 0; c < 3; ++c) {
        int j = idx32(cur[sub * 3 + c]);
        cval[c] = (j < N) && (cur[sub * 3 + c] != 0u);
        cj[c] = cval[c] ? j : 0;
        pj[c] = (const f32x4v*)(x + (size_t)cj[c] * D);
    }
    const f32x4v* xip = (const f32x4v*)(x + (size_t)rr * D);
#pragma unroll
    for (int t = 0; t < 16; ++t) {
        const f32x4v xv = xip[t];
#pragma unroll
        for (int c = 0; c < 3; ++c) {
            const f32x4v pv = pj[c][t];
            d[c] = fmaf(xv[0], pv[0], d[c]);
            d[c] = fmaf(xv[1], pv[1], d[c]);
            d[c] = fmaf(xv[2], pv[2], d[c]);
            d[c] = fmaf(xv[3], pv[3], d[c]);
        }
    }
    u64 F[K];
#pragma unroll
    for (int c = 0; c < 3; ++c) {
        float val = 2.f * d[c] - nxi - xxf[cj[c]];
        F[c] = cval[c] ? packKV(val, cj[c]) : 0ull;
    }
    F[3] = 0ull; F[4] = 0ull;
    // sort first 3 desc
    { u64 a0=F[0],a1=F[1],a2=F[2];
      if (a0 < a1) { u64 t0=a0; a0=a1; a1=t0; }
      if (a1 < a2) { u64 t0=a1; a1=a2; a2=t0; }
      if (a0 < a1) { u64 t0=a0; a0=a1; a1=t0; }
      F[0]=a0; F[1]=a1; F[2]=a2; }
#pragma unroll
    for (int mask = 1; mask <= 2; mask <<= 1) {
        u64 P[K];
#pragma unroll
        for (int m = 0; m < K; ++m) P[m] = __shfl_xor(F[m], mask);
        mergeKeep<K, K, K, u64>(F, P);
    }

    if (sub == 0 && vrow) {
#pragma unroll
        for (int m = 0; m < K; ++m) {
            int j = (int)(~(u32)F[m]);
            if ((unsigned)j < (unsigned)N && j != row) {
                float v = unpackV(F[m]);
                atomicAdd(out + (size_t)row * N + j, v);
                atomicAdd(out + (size_t)j * N + row, v);
            }
        }
    }
}

// ---------------------------------------------------------------------------
extern "C" void kernel_launch(void* const* d_in, const int* in_sizes, int n_in,
                              void* d_out, int out_size, void* d_ws, size_t ws_size,
                              hipStream_t stream) {
    const float* x = (const float*)d_in[0];
    const int N = in_sizes[0] / D;          // 10000
    float* out = (float*)d_out;

    // Workspace: xbA[625*2*64*8 bf16] | xxf[N] f32 | wsK[N*NSPLIT*LK] u32 (~7.5 MB)
    const size_t oXB = 0;
    const size_t oXX = ((size_t)NTILES * 2 * 64 * 8 * 2 + 255) & ~255ull;
    const size_t oWK = (oXX + (size_t)N * 4 + 255) & ~255ull;
    __bf16* xbA = (__bf16*)((char*)d_ws + oXB);
    float*  xxf = (float*)((char*)d_ws + oXX);
    u32*    wsK = (u32*)((char*)d_ws + oWK);

    const int prepThreads = NTILES * 2 * 64 + N;         // 90000
    prep<<<(prepThreads + 255) / 256, 256, 0, stream>>>(x, xbA, xxf, N);

    long long totalF4 = (long long)out_size / 4;         // 25e6
    const int nBlocksTotal = 3024;                       // 504 zero + 2520 compute slots
    const int nZero = (nBlocksTotal + 5) / 6;            // 504
    int f4PerZ = (int)((totalF4 + nZero - 1) / nZero);   // ~49604
    topk_zero_mfma<<<nBlocksTotal, 256, 0, stream>>>(
        xbA, xxf, N, wsK, out, totalF4, nZero, f4PerZ);

    rescore_scatter<<<ROWBLK, 256, 0, stream>>>(wsK, x, xxf, out, N);
}